// Round 4
// baseline (661.512 us; speedup 1.0000x reference)
//
#include <hip/hip_runtime.h>

// 2-layer GRU (T=1000 serial, B=512) + FC + log_softmax.
// Pass 1: ax[b,t] = x_t @ W1x + b1 (both gates) -> d_ws, per-lane (z,g) float2.
// Pass 2: 256 waves, each interleaves TWO batch elements. Skewed GRU1/GRU2
//         lane mapping (lanes 0..31 = GRU1 units, 32..51 = GRU2 units, one
//         step behind). h broadcast via 1 ds_write + 13 uniform ds_read_b128
//         per step (no readlane on the hot path); the partner element's FMA
//         stream hides the LDS turnaround and activation-chain latency.

typedef float v4f __attribute__((ext_vector_type(4)));

constexpr int FBINS  = 40;
constexpr int L1     = 32;
constexpr int L2     = 20;
constexpr int L3     = 16;
constexpr int NCLASS = 10;
constexpr int T      = 1000;
constexpr int KTOT   = L1 + L2;   // 52
constexpr float LOG2E = 1.4426950408889634f;
constexpr float LN2   = 0.6931471805599453f;

__device__ __forceinline__ float rl(float v, int l) {
    return __uint_as_float(__builtin_amdgcn_readlane(__float_as_uint(v), l));
}

// ---------------- pass 1: x-projection ----------------
constexpr int TCH = 100;
__global__ __launch_bounds__(256) void xproj_kernel(
    const float* __restrict__ xg,
    const float* __restrict__ wz1, const float* __restrict__ bz1,
    const float* __restrict__ wh1, const float* __restrict__ bh1,
    float* __restrict__ ax, int t0, int tcnt, int segcap)
{
    __shared__ float xs[TCH * FBINS];
    const int tid = threadIdx.x, lane = tid & 63;
    const int b   = blockIdx.x;
    const int lt0 = blockIdx.y * TCH;
    const int cnt = min(TCH, tcnt - lt0);
    const float* src = xg + ((size_t)b * T + t0 + lt0) * FBINS;
    const int ndw = cnt * FBINS;
    for (int i = tid; i < ndw; i += 256) xs[i] = src[i];
    __syncthreads();

    const int j = lane & 31;
    const float* wp = (lane < 32) ? wz1 : wh1;
    float w[FBINS];
    #pragma unroll
    for (int k = 0; k < FBINS; ++k) w[k] = wp[k * L1 + j];
    const float bias = (lane < 32) ? bz1[j] : bh1[j];
    const int slot = j * 2 + (lane >> 5);

    const int wv = tid >> 6;
    for (int lt = wv; lt < cnt; lt += 4) {
        const float* xp = xs + lt * FBINS;
        float a0 = bias, a1 = 0.f, a2 = 0.f, a3 = 0.f;
        #pragma unroll
        for (int k = 0; k < FBINS; k += 4) {
            a0 = fmaf(xp[k+0], w[k+0], a0);
            a1 = fmaf(xp[k+1], w[k+1], a1);
            a2 = fmaf(xp[k+2], w[k+2], a2);
            a3 = fmaf(xp[k+3], w[k+3], a3);
        }
        ax[((size_t)b * segcap + lt0 + lt) * 64 + slot] = (a0 + a1) + (a2 + a3);
    }
}

// ---------------- pass 2: interleaved recurrence ----------------
constexpr int GS = 4;
__global__ __launch_bounds__(64, 1) void rec_kernel(
    const float* __restrict__ ax,
    const float* __restrict__ wz1, const float* __restrict__ wh1,
    const float* __restrict__ wz2, const float* __restrict__ bz2,
    const float* __restrict__ wh2, const float* __restrict__ bh2,
    const float* __restrict__ w3,  const float* __restrict__ b3,
    const float* __restrict__ w4,  const float* __restrict__ b4,
    float* __restrict__ hws, float* __restrict__ outg,
    int tcnt, int segcap, int first, int last, int Bsz)
{
    __shared__ alignas(16) float hb[2][64];

    const int lane = threadIdx.x;
    const int j    = lane & 31;
    const bool lo  = lane < 32;
    const int j2   = (j < L2) ? j : 0;

    const int e0 = blockIdx.x * 2;
    int e1 = e0 + 1; if (e1 >= Bsz) e1 = e0;
    const bool dup = (e1 == e0);

    // shared per-lane weight columns (identical for both elements)
    float wZ[KTOT], wG[KTOT];
    #pragma unroll
    for (int k = 0; k < L1; ++k) {
        wZ[k] = lo ? wz1[(FBINS + k) * L1 + j] : wz2[k * L2 + j2];
        wG[k] = lo ? wh1[(FBINS + k) * L1 + j] : wh2[k * L2 + j2];
    }
    #pragma unroll
    for (int k = 0; k < L2; ++k) {
        wZ[L1 + k] = lo ? 0.f : wz2[(L1 + k) * L2 + j2];
        wG[L1 + k] = lo ? 0.f : wh2[(L1 + k) * L2 + j2];
    }
    const float initZ = lo ? 0.f : bz2[j2];
    const float initG = lo ? 0.f : bh2[j2];

    const float up0 = first ? 0.f : hws[e0 * 64 + 32 + j2];
    const float up1 = first ? 0.f : hws[e1 * 64 + 32 + j2];
    float hA = lo ? (first ? 0.f : hws[e0 * 64 + j]) : up0;
    float hB = lo ? (first ? 0.f : hws[e1 * 64 + j]) : up1;
    hb[0][lane] = hA;
    hb[1][lane] = hB;

    const float2* ap0 = (const float2*)ax + (size_t)e0 * segcap * 32 + j;
    const float2* ap1 = (const float2*)ax + (size_t)e1 * segcap * 32 + j;

    auto step = [&](float& h, float* hbp, float2 axv) {
        float sh[KTOT];
        const v4f* hp = (const v4f*)hbp;
        #pragma unroll
        for (int c = 0; c < KTOT / 4; ++c) {          // 13 broadcast b128 reads
            v4f t = hp[c];
            sh[4*c+0] = t.x; sh[4*c+1] = t.y; sh[4*c+2] = t.z; sh[4*c+3] = t.w;
        }
        float z0 = lo ? axv.x : initZ, z1 = 0.f, z2 = 0.f, z3 = 0.f;
        float g0 = lo ? axv.y : initG, g1 = 0.f, g2 = 0.f, g3 = 0.f;
        #pragma unroll
        for (int k = 0; k < KTOT; k += 4) {
            z0 = fmaf(sh[k+0], wZ[k+0], z0);
            z1 = fmaf(sh[k+1], wZ[k+1], z1);
            z2 = fmaf(sh[k+2], wZ[k+2], z2);
            z3 = fmaf(sh[k+3], wZ[k+3], z3);
            g0 = fmaf(sh[k+0], wG[k+0], g0);
            g1 = fmaf(sh[k+1], wG[k+1], g1);
            g2 = fmaf(sh[k+2], wG[k+2], g2);
            g3 = fmaf(sh[k+3], wG[k+3], g3);
        }
        float z = (z0 + z1) + (z2 + z3);
        float g = (g0 + g1) + (g2 + g3);
        float ez = __builtin_amdgcn_exp2f(-z * LOG2E);
        float s  = __builtin_amdgcn_rcpf(1.f + ez);
        float eg = __builtin_amdgcn_exp2f(-2.f * g * LOG2E);
        float r  = __builtin_amdgcn_rcpf(1.f + eg);
        float gt = fmaf(2.f, r, -1.f);
        h = fmaf(s, gt - h, h);
        hbp[lane] = h;
    };

    float2 a0A[GS], a0B[GS], a1A[GS], a1B[GS];
    const int ng = tcnt / GS;
    #pragma unroll
    for (int i = 0; i < GS; ++i) { a0A[i] = ap0[(size_t)i * 32];        a1A[i] = ap1[(size_t)i * 32]; }
    #pragma unroll
    for (int i = 0; i < GS; ++i) { a0B[i] = ap0[(size_t)(GS + i) * 32]; a1B[i] = ap1[(size_t)(GS + i) * 32]; }

    // group 0 with first-step skew fixup (upper lanes' step-0 output is junk)
    step(hA, &hb[0][0], a0A[0]);
    hA = lo ? hA : up0;  hb[0][lane] = hA;
    step(hB, &hb[1][0], a1A[0]);
    hB = lo ? hB : up1;  hb[1][lane] = hB;
    #pragma unroll
    for (int i = 1; i < GS; ++i) {
        step(hA, &hb[0][0], a0A[i]);
        step(hB, &hb[1][0], a1A[i]);
    }
    if (2 < ng) {
        #pragma unroll
        for (int i = 0; i < GS; ++i) { a0A[i] = ap0[(size_t)(2*GS+i)*32]; a1A[i] = ap1[(size_t)(2*GS+i)*32]; }
    }

    #pragma unroll 1
    for (int gp = 1; gp < ng; gp += 2) {
        #pragma unroll
        for (int i = 0; i < GS; ++i) {
            step(hA, &hb[0][0], a0B[i]);
            step(hB, &hb[1][0], a1B[i]);
        }
        if (gp + 2 < ng) {
            #pragma unroll
            for (int i = 0; i < GS; ++i) { a0B[i] = ap0[(size_t)((gp+2)*GS+i)*32]; a1B[i] = ap1[(size_t)((gp+2)*GS+i)*32]; }
        }
        if (gp + 1 < ng) {
            #pragma unroll
            for (int i = 0; i < GS; ++i) {
                step(hA, &hb[0][0], a0A[i]);
                step(hB, &hb[1][0], a1A[i]);
            }
            if (gp + 3 < ng) {
                #pragma unroll
                for (int i = 0; i < GS; ++i) { a0A[i] = ap0[(size_t)((gp+3)*GS+i)*32]; a1A[i] = ap1[(size_t)((gp+3)*GS+i)*32]; }
            }
        }
    }

    // save h1 (lower) before epilogue junks it, then finish last GRU2 step
    if (!last && lo) {
        hws[e0 * 64 + j] = hA;
        if (!dup) hws[e1 * 64 + j] = hB;
    }
    step(hA, &hb[0][0], make_float2(0.f, 0.f));
    step(hB, &hb[1][0], make_float2(0.f, 0.f));
    if (!last) {
        if (!lo && j < L2) {
            hws[e0 * 64 + 32 + j] = hA;
            if (!dup) hws[e1 * 64 + 32 + j] = hB;
        }
        return;
    }

    // ---- tail: FC3+ReLU, FC4, log_softmax (once per element) ----
    auto tail = [&](const float* hbp, float* op) {
        float s2[L2];
        #pragma unroll
        for (int c = 0; c < L2 / 4; ++c) {
            v4f t = ((const v4f*)(hbp + 32))[c];
            s2[4*c+0] = t.x; s2[4*c+1] = t.y; s2[4*c+2] = t.z; s2[4*c+3] = t.w;
        }
        float a3 = 0.f;
        if (lane < L3) {
            a3 = b3[lane];
            #pragma unroll
            for (int k = 0; k < L2; ++k) a3 = fmaf(s2[k], w3[k * L3 + lane], a3);
            a3 = fmaxf(a3, 0.f);
        }
        float s3[L3];
        #pragma unroll
        for (int k = 0; k < L3; ++k) s3[k] = rl(a3, k);
        float a4 = 0.f;
        if (lane < NCLASS) {
            a4 = b4[lane];
            #pragma unroll
            for (int k = 0; k < L3; ++k) a4 = fmaf(s3[k], w4[k * NCLASS + lane], a4);
        }
        float s4[NCLASS];
        #pragma unroll
        for (int k = 0; k < NCLASS; ++k) s4[k] = rl(a4, k);
        float m = s4[0];
        #pragma unroll
        for (int k = 1; k < NCLASS; ++k) m = fmaxf(m, s4[k]);
        float ss = 0.f;
        #pragma unroll
        for (int k = 0; k < NCLASS; ++k)
            ss += __builtin_amdgcn_exp2f((s4[k] - m) * LOG2E);
        float lse = m + __builtin_amdgcn_logf(ss) * LN2;
        if (lane < NCLASS) op[lane] = s4[lane] - lse;
    };
    tail(&hb[0][0], outg + e0 * NCLASS);
    tail(&hb[1][0], outg + e1 * NCLASS);
}

extern "C" void kernel_launch(void* const* d_in, const int* in_sizes, int n_in,
                              void* d_out, int out_size, void* d_ws, size_t ws_size,
                              hipStream_t stream) {
    const float* x   = (const float*)d_in[0];
    const float* wz1 = (const float*)d_in[1];
    const float* bz1 = (const float*)d_in[2];
    const float* wh1 = (const float*)d_in[3];
    const float* bh1 = (const float*)d_in[4];
    const float* wz2 = (const float*)d_in[5];
    const float* bz2 = (const float*)d_in[6];
    const float* wh2 = (const float*)d_in[7];
    const float* bh2 = (const float*)d_in[8];
    const float* w3  = (const float*)d_in[9];
    const float* b3  = (const float*)d_in[10];
    const float* w4  = (const float*)d_in[11];
    const float* b4  = (const float*)d_in[12];
    float* out = (float*)d_out;

    const int Bsz = in_sizes[0] / (T * FBINS);          // 512

    float* hws = (float*)d_ws;
    float* axw = hws + (size_t)Bsz * 64;
    const size_t hbytes = (size_t)Bsz * 64 * sizeof(float);
    const size_t per_t  = (size_t)Bsz * 64 * sizeof(float);

    int segT = T;
    if (ws_size < hbytes + (size_t)T * per_t) {
        size_t avail = (ws_size > hbytes) ? ws_size - hbytes : 0;
        size_t s = avail / per_t;
        segT = (s > (size_t)T) ? T : (int)s;
        segT &= ~7;
        if (segT < 8) segT = 8;
    }

    const int nblk = (Bsz + 1) / 2;
    for (int t0 = 0; t0 < T; t0 += segT) {
        const int tc = (T - t0 < segT) ? (T - t0) : segT;
        dim3 g1(Bsz, (tc + TCH - 1) / TCH);
        xproj_kernel<<<g1, dim3(256), 0, stream>>>(x, wz1, bz1, wh1, bh1,
                                                   axw, t0, tc, segT);
        rec_kernel<<<dim3(nblk), dim3(64), 0, stream>>>(axw,
            wz1, wh1, wz2, bz2, wh2, bh2, w3, b3, w4, b4,
            hws, out, tc, segT, t0 == 0 ? 1 : 0, (t0 + tc >= T) ? 1 : 0, Bsz);
    }
}

// Round 5
// 599.588 us; speedup vs baseline: 1.1033x; 1.1033x over previous
//
#include <hip/hip_runtime.h>

// 2-layer GRU (T=1000 serial, B=512) + FC + log_softmax.
// Pass 1: ax[b,t] = x_t @ W1x + b1 (both gates) -> d_ws, per-lane (z,g) float2.
// Pass 2: 256 waves, each interleaving TWO batch elements (skewed GRU1/GRU2
//         lane mapping: lanes 0..31 = GRU1 units @ step t, lanes 32..51 =
//         GRU2 units @ step t-1). Broadcasts rebuilt every round:
//           element A: 52 x v_readlane -> SGPR (scalar FMA stream)
//           element B: 52 x ds_bpermute (uniform idx) -> VGPR (packed FMA)
//         B's bpermute latency hides under A's readlane+FMA issue; A's act
//         chain hides under B's FMA issue. No LDS storage on the hot path.

typedef float v2f __attribute__((ext_vector_type(2)));

constexpr int FBINS  = 40;
constexpr int L1     = 32;
constexpr int L2     = 20;
constexpr int L3     = 16;
constexpr int NCLASS = 10;
constexpr int T      = 1000;
constexpr int KTOT   = L1 + L2;   // 52
constexpr float LOG2E = 1.4426950408889634f;
constexpr float LN2   = 0.6931471805599453f;

__device__ __forceinline__ float rl(float v, int l) {
    return __uint_as_float(__builtin_amdgcn_readlane(__float_as_uint(v), l));
}
__device__ __forceinline__ float bperm(float v, int srclane) {
    return __uint_as_float(__builtin_amdgcn_ds_bpermute(srclane * 4,
                                                        __float_as_uint(v)));
}

// ---------------- pass 1: x-projection ----------------
constexpr int TCH = 100;
__global__ __launch_bounds__(256) void xproj_kernel(
    const float* __restrict__ xg,
    const float* __restrict__ wz1, const float* __restrict__ bz1,
    const float* __restrict__ wh1, const float* __restrict__ bh1,
    float* __restrict__ ax, int t0, int tcnt, int segcap)
{
    __shared__ float xs[TCH * FBINS];
    const int tid = threadIdx.x, lane = tid & 63;
    const int b   = blockIdx.x;
    const int lt0 = blockIdx.y * TCH;
    const int cnt = min(TCH, tcnt - lt0);
    const float* src = xg + ((size_t)b * T + t0 + lt0) * FBINS;
    const int ndw = cnt * FBINS;
    for (int i = tid; i < ndw; i += 256) xs[i] = src[i];
    __syncthreads();

    const int j = lane & 31;
    const float* wp = (lane < 32) ? wz1 : wh1;
    float w[FBINS];
    #pragma unroll
    for (int k = 0; k < FBINS; ++k) w[k] = wp[k * L1 + j];
    const float bias = (lane < 32) ? bz1[j] : bh1[j];
    const int slot = j * 2 + (lane >> 5);

    const int wv = tid >> 6;
    for (int lt = wv; lt < cnt; lt += 4) {
        const float* xp = xs + lt * FBINS;
        float a0 = bias, a1 = 0.f, a2 = 0.f, a3 = 0.f;
        #pragma unroll
        for (int k = 0; k < FBINS; k += 4) {
            a0 = fmaf(xp[k+0], w[k+0], a0);
            a1 = fmaf(xp[k+1], w[k+1], a1);
            a2 = fmaf(xp[k+2], w[k+2], a2);
            a3 = fmaf(xp[k+3], w[k+3], a3);
        }
        ax[((size_t)b * segcap + lt0 + lt) * 64 + slot] = (a0 + a1) + (a2 + a3);
    }
}

// ---------------- pass 2: interleaved recurrence ----------------
constexpr int GS = 4;
__global__ __launch_bounds__(64, 1) void rec_kernel(
    const float* __restrict__ ax,
    const float* __restrict__ wz1, const float* __restrict__ wh1,
    const float* __restrict__ wz2, const float* __restrict__ bz2,
    const float* __restrict__ wh2, const float* __restrict__ bh2,
    const float* __restrict__ w3,  const float* __restrict__ b3,
    const float* __restrict__ w4,  const float* __restrict__ b4,
    float* __restrict__ hws, float* __restrict__ outg,
    int tcnt, int segcap, int first, int last, int Bsz)
{
    const int lane = threadIdx.x;
    const int j    = lane & 31;
    const bool lo  = lane < 32;
    const int j2   = (j < L2) ? j : 0;

    const int e0 = blockIdx.x * 2;
    int e1 = e0 + 1; if (e1 >= Bsz) e1 = e0;
    const bool dup = (e1 == e0);

    // shared per-lane weight columns, stored as v2f pairs (scalar access via .x/.y)
    v2f wZ[KTOT / 2], wG[KTOT / 2];
    #pragma unroll
    for (int k = 0; k < L1; k += 2) {
        wZ[k/2].x = lo ? wz1[(FBINS + k)     * L1 + j] : wz2[k       * L2 + j2];
        wZ[k/2].y = lo ? wz1[(FBINS + k + 1) * L1 + j] : wz2[(k + 1) * L2 + j2];
        wG[k/2].x = lo ? wh1[(FBINS + k)     * L1 + j] : wh2[k       * L2 + j2];
        wG[k/2].y = lo ? wh1[(FBINS + k + 1) * L1 + j] : wh2[(k + 1) * L2 + j2];
    }
    #pragma unroll
    for (int k = 0; k < L2; k += 2) {
        wZ[(L1+k)/2].x = lo ? 0.f : wz2[(L1 + k)     * L2 + j2];
        wZ[(L1+k)/2].y = lo ? 0.f : wz2[(L1 + k + 1) * L2 + j2];
        wG[(L1+k)/2].x = lo ? 0.f : wh2[(L1 + k)     * L2 + j2];
        wG[(L1+k)/2].y = lo ? 0.f : wh2[(L1 + k + 1) * L2 + j2];
    }
    const float initZ = lo ? 0.f : bz2[j2];
    const float initG = lo ? 0.f : bh2[j2];

    const float up0 = first ? 0.f : hws[e0 * 64 + 32 + j2];
    const float up1 = first ? 0.f : hws[e1 * 64 + 32 + j2];
    float hA = lo ? (first ? 0.f : hws[e0 * 64 + j]) : up0;
    float hB = lo ? (first ? 0.f : hws[e1 * 64 + j]) : up1;

    const float2* ap0 = (const float2*)ax + (size_t)e0 * segcap * 32 + j;
    const float2* ap1 = (const float2*)ax + (size_t)e1 * segcap * 32 + j;

    auto act = [&](float z, float g, float h) {
        float ez = __builtin_amdgcn_exp2f(-z * LOG2E);        // sigmoid(z)
        float s  = __builtin_amdgcn_rcpf(1.f + ez);
        float eg = __builtin_amdgcn_exp2f(-2.f * g * LOG2E);  // tanh(g)
        float r  = __builtin_amdgcn_rcpf(1.f + eg);
        float gt = fmaf(2.f, r, -1.f);
        return fmaf(s, gt - h, h);                            // (1-z)h + z*g
    };

    auto roundfn = [&](float2 axA, float2 axB) {
        // ---- B broadcasts first (DS pipe; latency hides under A's stream)
        v2f shB[KTOT / 2];
        #pragma unroll
        for (int k = 0; k < KTOT; k += 2) {
            shB[k/2].x = bperm(hB, k);
            shB[k/2].y = bperm(hB, k + 1);
        }
        // ---- A broadcasts (VALU -> SGPR)
        float shA[KTOT];
        #pragma unroll
        for (int k = 0; k < KTOT; ++k) shA[k] = rl(hA, k);

        // ---- A dot (scalar FMA, SGPR broadcast operand)
        float z0 = lo ? axA.x : initZ, z1 = 0.f, z2 = 0.f, z3 = 0.f;
        float g0 = lo ? axA.y : initG, g1 = 0.f, g2 = 0.f, g3 = 0.f;
        #pragma unroll
        for (int k = 0; k < KTOT; k += 4) {
            z0 = fmaf(shA[k+0], wZ[k/2].x,   z0);
            z1 = fmaf(shA[k+1], wZ[k/2].y,   z1);
            z2 = fmaf(shA[k+2], wZ[k/2+1].x, z2);
            z3 = fmaf(shA[k+3], wZ[k/2+1].y, z3);
            g0 = fmaf(shA[k+0], wG[k/2].x,   g0);
            g1 = fmaf(shA[k+1], wG[k/2].y,   g1);
            g2 = fmaf(shA[k+2], wG[k/2+1].x, g2);
            g3 = fmaf(shA[k+3], wG[k/2+1].y, g3);
        }
        float zA = (z0 + z1) + (z2 + z3);
        float gA = (g0 + g1) + (g2 + g3);

        // ---- B dot (packed FMA, VGPR broadcast operand)
        v2f bz0 = {lo ? axB.x : initZ, 0.f}, bz1v = {0.f, 0.f};
        v2f bg0 = {lo ? axB.y : initG, 0.f}, bg1v = {0.f, 0.f};
        #pragma unroll
        for (int c = 0; c < KTOT / 2; c += 2) {
            bz0  = __builtin_elementwise_fma(shB[c],   wZ[c],   bz0);
            bz1v = __builtin_elementwise_fma(shB[c+1], wZ[c+1], bz1v);
            bg0  = __builtin_elementwise_fma(shB[c],   wG[c],   bg0);
            bg1v = __builtin_elementwise_fma(shB[c+1], wG[c+1], bg1v);
        }
        v2f bzs = bz0 + bz1v, bgs = bg0 + bg1v;
        float zB = bzs.x + bzs.y;
        float gB = bgs.x + bgs.y;

        // ---- activations + h updates (two independent serial chains)
        hA = act(zA, gA, hA);
        hB = act(zB, gB, hB);
    };

    // ---- pipelined loop, GS-step groups, double-buffered register prefetch
    float2 a0A[GS], a0B[GS], a1A[GS], a1B[GS];
    const int ng = tcnt / GS;                    // tcnt multiple of 8 -> even
    #pragma unroll
    for (int i = 0; i < GS; ++i) { a0A[i] = ap0[(size_t)i * 32];        a1A[i] = ap1[(size_t)i * 32]; }
    #pragma unroll
    for (int i = 0; i < GS; ++i) { a0B[i] = ap0[(size_t)(GS + i) * 32]; a1B[i] = ap1[(size_t)(GS + i) * 32]; }

    // group 0 with first-round skew fixup (upper lanes' step-0 output is junk;
    // sh is rebuilt each round, so restoring h suffices)
    roundfn(a0A[0], a1A[0]);
    hA = lo ? hA : up0;
    hB = lo ? hB : up1;
    #pragma unroll
    for (int i = 1; i < GS; ++i) roundfn(a0A[i], a1A[i]);
    if (2 < ng) {
        #pragma unroll
        for (int i = 0; i < GS; ++i) { a0A[i] = ap0[(size_t)(2*GS+i)*32]; a1A[i] = ap1[(size_t)(2*GS+i)*32]; }
    }

    #pragma unroll 1
    for (int gp = 1; gp < ng; gp += 2) {
        #pragma unroll
        for (int i = 0; i < GS; ++i) roundfn(a0B[i], a1B[i]);
        if (gp + 2 < ng) {
            #pragma unroll
            for (int i = 0; i < GS; ++i) { a0B[i] = ap0[(size_t)((gp+2)*GS+i)*32]; a1B[i] = ap1[(size_t)((gp+2)*GS+i)*32]; }
        }
        if (gp + 1 < ng) {
            #pragma unroll
            for (int i = 0; i < GS; ++i) roundfn(a0A[i], a1A[i]);
            if (gp + 3 < ng) {
                #pragma unroll
                for (int i = 0; i < GS; ++i) { a0A[i] = ap0[(size_t)((gp+3)*GS+i)*32]; a1A[i] = ap1[(size_t)((gp+3)*GS+i)*32]; }
            }
        }
    }

    // save h1 (lower) before epilogue junks it, then finish last GRU2 step
    if (!last && lo) {
        hws[e0 * 64 + j] = hA;
        if (!dup) hws[e1 * 64 + j] = hB;
    }
    roundfn(make_float2(0.f, 0.f), make_float2(0.f, 0.f));
    if (!last) {
        if (!lo && j < L2) {
            hws[e0 * 64 + 32 + j] = hA;
            if (!dup) hws[e1 * 64 + 32 + j] = hB;
        }
        return;
    }

    // ---- tail: FC3+ReLU, FC4, log_softmax (per element; h2 = upper lanes of h)
    auto tail = [&](float hfin, float* op) {
        float s2[L2];
        #pragma unroll
        for (int k = 0; k < L2; ++k) s2[k] = rl(hfin, 32 + k);
        float a3 = 0.f;
        if (lane < L3) {
            a3 = b3[lane];
            #pragma unroll
            for (int k = 0; k < L2; ++k) a3 = fmaf(s2[k], w3[k * L3 + lane], a3);
            a3 = fmaxf(a3, 0.f);
        }
        float s3[L3];
        #pragma unroll
        for (int k = 0; k < L3; ++k) s3[k] = rl(a3, k);
        float a4 = 0.f;
        if (lane < NCLASS) {
            a4 = b4[lane];
            #pragma unroll
            for (int k = 0; k < L3; ++k) a4 = fmaf(s3[k], w4[k * NCLASS + lane], a4);
        }
        float s4[NCLASS];
        #pragma unroll
        for (int k = 0; k < NCLASS; ++k) s4[k] = rl(a4, k);
        float m = s4[0];
        #pragma unroll
        for (int k = 1; k < NCLASS; ++k) m = fmaxf(m, s4[k]);
        float ss = 0.f;
        #pragma unroll
        for (int k = 0; k < NCLASS; ++k)
            ss += __builtin_amdgcn_exp2f((s4[k] - m) * LOG2E);
        float lse = m + __builtin_amdgcn_logf(ss) * LN2;
        if (lane < NCLASS) op[lane] = s4[lane] - lse;
    };
    tail(hA, outg + e0 * NCLASS);
    tail(hB, outg + e1 * NCLASS);
}

extern "C" void kernel_launch(void* const* d_in, const int* in_sizes, int n_in,
                              void* d_out, int out_size, void* d_ws, size_t ws_size,
                              hipStream_t stream) {
    const float* x   = (const float*)d_in[0];
    const float* wz1 = (const float*)d_in[1];
    const float* bz1 = (const float*)d_in[2];
    const float* wh1 = (const float*)d_in[3];
    const float* bh1 = (const float*)d_in[4];
    const float* wz2 = (const float*)d_in[5];
    const float* bz2 = (const float*)d_in[6];
    const float* wh2 = (const float*)d_in[7];
    const float* bh2 = (const float*)d_in[8];
    const float* w3  = (const float*)d_in[9];
    const float* b3  = (const float*)d_in[10];
    const float* w4  = (const float*)d_in[11];
    const float* b4  = (const float*)d_in[12];
    float* out = (float*)d_out;

    const int Bsz = in_sizes[0] / (T * FBINS);          // 512

    float* hws = (float*)d_ws;
    float* axw = hws + (size_t)Bsz * 64;
    const size_t hbytes = (size_t)Bsz * 64 * sizeof(float);
    const size_t per_t  = (size_t)Bsz * 64 * sizeof(float);

    int segT = T;
    if (ws_size < hbytes + (size_t)T * per_t) {
        size_t avail = (ws_size > hbytes) ? ws_size - hbytes : 0;
        size_t s = avail / per_t;
        segT = (s > (size_t)T) ? T : (int)s;
        segT &= ~7;
        if (segT < 8) segT = 8;
    }

    const int nblk = (Bsz + 1) / 2;
    for (int t0 = 0; t0 < T; t0 += segT) {
        const int tc = (T - t0 < segT) ? (T - t0) : segT;
        dim3 g1(Bsz, (tc + TCH - 1) / TCH);
        xproj_kernel<<<g1, dim3(256), 0, stream>>>(x, wz1, bz1, wh1, bh1,
                                                   axw, t0, tc, segT);
        rec_kernel<<<dim3(nblk), dim3(64), 0, stream>>>(axw,
            wz1, wh1, wz2, bz2, wh2, bh2, w3, b3, w4, b4,
            hws, out, tc, segT, t0 == 0 ? 1 : 0, (t0 + tc >= T) ? 1 : 0, Bsz);
    }
}